// Round 4
// baseline (549.145 us; speedup 1.0000x reference)
//
#include <hip/hip_runtime.h>
#include <stdint.h>

typedef unsigned short u16;
typedef unsigned int u32;
typedef __bf16 bf16x8 __attribute__((ext_vector_type(8)));
typedef float floatx4 __attribute__((ext_vector_type(4)));

static constexpr int NC = 120000;
static constexpr int NF = 240000;

__device__ __forceinline__ float bf2f(u16 u) {
    union { u32 i; float f; } v; v.i = ((u32)u) << 16; return v.f;
}
__device__ __forceinline__ u16 f2bf(float f) {
    union { float f; u32 i; } v; v.f = f;
    u32 r = v.i + 0x7FFFu + ((v.i >> 16) & 1u);
    return (u16)(r >> 16);
}

// xp[i] = bf16(feats_x[i] + feats_skip[i]) for i < NC rows; row NC zeroed (pad row).
__global__ void add_pad_k(const float* __restrict__ a, const float* __restrict__ b,
                          u16* __restrict__ xp) {
    int idx = blockIdx.x * blockDim.x + threadIdx.x;  // 4 elements per thread
    if (idx >= (NC + 1) * 32) return;
    uint2 vo;
    if (idx < NC * 32) {
        float4 va = ((const float4*)a)[idx];
        float4 vb = ((const float4*)b)[idx];
        vo.x = (u32)f2bf(va.x + vb.x) | ((u32)f2bf(va.y + vb.y) << 16);
        vo.y = (u32)f2bf(va.z + vb.z) | ((u32)f2bf(va.w + vb.w) << 16);
    } else {
        vo.x = vo.y = 0u;
    }
    ((uint2*)xp)[idx] = vo;
}

// Fragment-major weight layout: Wt[k][kc][nt][lane][j] = bf16(W[k][ci][co])
// with ci = kc*32 + (lane>>4)*8 + j, co = nt*16 + (lane&15).
__global__ void transpose_w_k(const float* __restrict__ W, u16* __restrict__ Wt,
                              int K, int Cin) {
    int idx = blockIdx.x * blockDim.x + threadIdx.x;
    if (idx >= K * Cin * 64) return;
    int per = Cin * 64;
    int k = idx / per, rem = idx - k * per;
    int kc = rem >> 11;             // rem / 2048
    int r2 = rem & 2047;
    int nt = r2 >> 9, lane = (r2 >> 3) & 63, j = r2 & 7;
    int ci = kc * 32 + (lane >> 4) * 8 + j;
    int co = nt * 16 + (lane & 15);
    Wt[idx] = f2bf(W[(size_t)(k * Cin + ci) * 64 + co]);
}

// Upsample slots (parity structure of k=3,s=2,p=1 inverse conv):
// slot 0 = tap 13 (even fine rows, identity); slot 8 = tap 26 (odd rows,
// identity); slots 1..7 = the other even-parity taps (12% density each).
__device__ __forceinline__ int upslot_to_k(int s) {
    if (s == 0) return 13;
    int e = s - 1;
    return 18 * ((e >> 2) & 1) + 6 * ((e >> 1) & 1) + 2 * (e & 1);
}
__global__ void transpose_wup_k(const float* __restrict__ W, u16* __restrict__ Wt) {
    int idx = blockIdx.x * blockDim.x + threadIdx.x;
    if (idx >= 9 * 4096) return;
    int s = idx >> 12, rem = idx & 4095;
    int kc = rem >> 11, r2 = rem & 2047;
    int nt = r2 >> 9, lane = (r2 >> 3) & 63, j = r2 & 7;
    int ci = kc * 32 + (lane >> 4) * 8 + j;
    int co = nt * 16 + (lane & 15);
    int k = upslot_to_k(s);
    Wt[idx] = f2bf(W[(size_t)(k * 64 + ci) * 64 + co]);
}

// Per-tap valid-pair counts (valid pairs are a sorted contiguous prefix; dummy
// pairs carry out == n_out). Binary search per tap, then per-set item prefix
// (items = 256-pair chunks). meta layout per set: [0]=total items,
// [1..T]=item prefix, [1+T..1+2T]=counts.  Sets: A(26 taps, +0), BC(16, +64),
// U(7, +128).
__global__ void counts_k(const int* __restrict__ p33, const int* __restrict__ p13,
                         const int* __restrict__ p31, const int* __restrict__ pup,
                         int* __restrict__ meta) {
    __shared__ int cl[64];
    const int t = threadIdx.x;
    const int* pp = nullptr;
    int n_out = NC;
    if (t < 26) {
        int k = t + (t >= 13);
        pp = p33 + (size_t)k * 2 * NC;
    } else if (t >= 32 && t < 48) {
        int j = t - 32, w = j >> 3, jj = j & 7, k = jj + (jj >= 4);
        pp = (w ? p31 : p13) + (size_t)k * 2 * NC;
    } else if (t >= 56 && t < 63) {
        const int kup[7] = {0, 2, 6, 8, 18, 20, 24};
        pp = pup + (size_t)kup[t - 56] * 2 * NC;
        n_out = NF;
    }
    if (pp) {
        int lo = 0, hi = NC;
        while (lo < hi) {
            int mid = (lo + hi) >> 1;
            if (pp[2 * mid + 1] < n_out) lo = mid + 1; else hi = mid;
        }
        cl[t] = lo;
    }
    __syncthreads();
    if (t == 0) {
        int acc = 0;
        for (int i = 0; i < 26; ++i) {
            meta[1 + i] = acc; meta[1 + 26 + i] = cl[i];
            acc += (cl[i] + 255) >> 8;
        }
        meta[0] = acc;
    }
    if (t == 1) {
        int acc = 0;
        for (int i = 0; i < 16; ++i) {
            meta[65 + i] = acc; meta[65 + 16 + i] = cl[32 + i];
            acc += (cl[32 + i] + 255) >> 8;
        }
        meta[64] = acc;
    }
    if (t == 2) {
        int acc = 0;
        for (int i = 0; i < 7; ++i) {
            meta[129 + i] = acc; meta[129 + 7 + i] = cl[56 + i];
            acc += (cl[56 + i] + 255) >> 8;
        }
        meta[128] = acc;
    }
}

// Dense (identity-tap) GEMM: out[r] = feats[r] @ W, direct rows, fp32 out.
// DUAL: two weight sets / two outputs from the same A rows (convB+convC fused;
// upsample even+odd identity halves fused). 128 rows per block (4 waves x 2
// tiles of 16).
template <int TCIN, bool DUAL>
__global__ __launch_bounds__(256, 2) void dense_k(
    const u16* __restrict__ feats, const u16* __restrict__ W0,
    const u16* __restrict__ W1, float* __restrict__ out0,
    float* __restrict__ out1, int nrows) {
    constexpr int KC = TCIN / 32;
    const int tid = threadIdx.x;
    const int wave = tid >> 6, lane = tid & 63;
    const int l15 = lane & 15, quad = lane >> 4;
    bf16x8 b0[KC][4], b1[DUAL ? KC : 1][4];
#pragma unroll
    for (int kc = 0; kc < KC; ++kc)
#pragma unroll
        for (int nt = 0; nt < 4; ++nt) {
            b0[kc][nt] = *(const bf16x8*)(W0 + ((kc * 4 + nt) * 64 + lane) * 8);
            if (DUAL) b1[kc][nt] = *(const bf16x8*)(W1 + ((kc * 4 + nt) * 64 + lane) * 8);
        }
#pragma unroll
    for (int i = 0; i < 2; ++i) {
        const int row0 = (int)blockIdx.x * 128 + wave * 32 + i * 16;
        int r = row0 + l15;
        const u16* ap = feats + (size_t)min(r, nrows) * TCIN + quad * 8;  // row nrows = zero pad
        bf16x8 a[KC];
#pragma unroll
        for (int kc = 0; kc < KC; ++kc) a[kc] = *(const bf16x8*)(ap + kc * 32);
        floatx4 ac0[4], ac1[4];
#pragma unroll
        for (int nt = 0; nt < 4; ++nt) { ac0[nt] = (floatx4)(0.0f); ac1[nt] = (floatx4)(0.0f); }
#pragma unroll
        for (int kc = 0; kc < KC; ++kc)
#pragma unroll
            for (int nt = 0; nt < 4; ++nt) {
                ac0[nt] = __builtin_amdgcn_mfma_f32_16x16x32_bf16(a[kc], b0[kc][nt], ac0[nt], 0, 0, 0);
                if (DUAL)
                    ac1[nt] = __builtin_amdgcn_mfma_f32_16x16x32_bf16(a[kc], b1[kc][nt], ac1[nt], 0, 0, 0);
            }
#pragma unroll
        for (int nt = 0; nt < 4; ++nt)
#pragma unroll
            for (int rr = 0; rr < 4; ++rr) {
                int orow = row0 + quad * 4 + rr;
                if (orow < nrows) {
                    size_t oi = (size_t)orow * 64 + nt * 16 + l15;
                    out0[oi] = ac0[nt][rr];
                    if (DUAL) out1[oi] = ac1[nt][rr];
                }
            }
    }
}

// Pair-compacted sparse-tap GEMM + atomic fp32 scatter-add.
// Work items = 256-pair chunks of one tap (grid-stride over a device-computed
// worklist). Per item: stage the tap's weight block to LDS once, then each of
// the 4 waves runs 4 sequential 16-pair MFMA tiles (A double-buffered in
// registers). Valid pairs are a contiguous sorted prefix of each tap's pair
// list; masked pairs gather the zero pad row and skip the scatter. Out rows
// are unique within a tap -> atomic contention only across taps (~3/row).
// Atomics are fire-and-forget (no return) -> no waitcnt stall.
// MODE 0: convA   (26 taps, pairs33, WtA,  out rawA32)
// MODE 1: convB+C (16 taps, pairs13/pairs31, Wt1/Wt2, rawB32/rawC32)
// MODE 2: upsample (7 taps, pairs_up, WtU slots 1..7, outp, n_out = NF)
template <int TCIN, int MODE, int T>
__global__ __launch_bounds__(256, 2) void sparse_k(
    const u16* __restrict__ feats,
    const int* __restrict__ P0, const int* __restrict__ P1,
    const u16* __restrict__ W0, const u16* __restrict__ W1,
    float* __restrict__ out0, float* __restrict__ out1,
    const int* __restrict__ meta, int n_out) {
    constexpr int KC = TCIN / 32;
    constexpr int NW = TCIN * 64 / 8;
    constexpr int NST = NW / 256;
    __shared__ bf16x8 wlds[NW];
    const int tid = threadIdx.x;
    const int wave = tid >> 6, lane = tid & 63;
    const int l15 = lane & 15, quad = lane >> 4;
    const int total = meta[0];
    for (int item = (int)blockIdx.x; item < total; item += (int)gridDim.x) {
        int t = 0;
#pragma unroll
        for (int i = 1; i < T; ++i) t += (item >= meta[1 + i]);
        const int cnt = meta[1 + T + t];
        const int* pp;
        const u16* wt;
        float* op;
        if (MODE == 0) {
            int k = t + (t >= 13);
            pp = P0 + (size_t)k * 2 * NC;
            wt = W0 + (size_t)k * TCIN * 64;
            op = out0;
        } else if (MODE == 1) {
            int j = t & 7, k = j + (j >= 4);
            pp = (t >= 8 ? P1 : P0) + (size_t)k * 2 * NC;
            wt = (t >= 8 ? W1 : W0) + (size_t)k * TCIN * 64;
            op = t >= 8 ? out1 : out0;
        } else {
            const int kup[7] = {0, 2, 6, 8, 18, 20, 24};
            pp = P0 + (size_t)kup[t] * 2 * NC;
            wt = W0 + (size_t)(t + 1) * TCIN * 64;
            op = out0;
        }
        __syncthreads();   // previous item's LDS reads complete
#pragma unroll
        for (int s = 0; s < NST; ++s) wlds[tid + s * 256] = ((const bf16x8*)wt)[tid + s * 256];
        __syncthreads();
        const int pbase = (item - meta[1 + t]) * 256 + wave * 64;
        bf16x8 abuf[2][KC];
        {
            int p = pbase + l15;
            int in = (p >= cnt) ? NC : P0[0];  // placeholder init, overwritten below
            in = (p >= cnt) ? NC : pp[2 * min(p, NC - 1)];
            const u16* ap = feats + (size_t)in * TCIN + quad * 8;
#pragma unroll
            for (int kc = 0; kc < KC; ++kc) abuf[0][kc] = *(const bf16x8*)(ap + kc * 32);
        }
#pragma unroll
        for (int i = 0; i < 4; ++i) {
            const int cur = i & 1, nxt = cur ^ 1;
            const int tb = pbase + i * 16;
            if (i + 1 < 4) {
                int p = tb + 16 + l15;
                int in = (p >= cnt) ? NC : pp[2 * min(p, NC - 1)];
                const u16* ap = feats + (size_t)in * TCIN + quad * 8;
#pragma unroll
                for (int kc = 0; kc < KC; ++kc) abuf[nxt][kc] = *(const bf16x8*)(ap + kc * 32);
            }
            if (tb < cnt) {
                floatx4 acc[4];
#pragma unroll
                for (int nt = 0; nt < 4; ++nt) acc[nt] = (floatx4)(0.0f);
#pragma unroll
                for (int kc = 0; kc < KC; ++kc)
#pragma unroll
                    for (int nt = 0; nt < 4; ++nt)
                        acc[nt] = __builtin_amdgcn_mfma_f32_16x16x32_bf16(
                            abuf[cur][kc], wlds[(kc * 4 + nt) * 64 + lane], acc[nt], 0, 0, 0);
#pragma unroll
                for (int r = 0; r < 4; ++r) {
                    int pr = tb + quad * 4 + r;
                    if (pr < cnt) {
                        int o = pp[2 * min(pr, NC - 1) + 1];
                        if (o < n_out) {
                            size_t ob = (size_t)o * 64 + l15;
#pragma unroll
                            for (int nt = 0; nt < 4; ++nt)
                                atomicAdd(&op[ob + nt * 16], acc[nt][r]);
                        }
                    }
                }
            }
        }
    }
}

// Per-channel stats over one fp32 [NC][64] buffer (optional leaky first).
template <bool LEAKY>
__global__ void stats_f32_k(const float* __restrict__ raw, float* __restrict__ sums,
                            int nblk) {
    int tid = threadIdx.x;
    int wave = tid >> 6, c = tid & 63;
    int gw = (int)blockIdx.x * 4 + wave;
    int GW = nblk * 4;
    float s = 0.f, q = 0.f;
    for (int r = gw; r < NC; r += GW) {
        float v = raw[(size_t)r * 64 + c];
        if (LEAKY) v = v > 0.f ? v : 0.01f * v;
        s += v; q += v * v;
    }
    __shared__ float sbm[4][64], qbm[4][64];
    sbm[wave][c] = s; qbm[wave][c] = q;
    __syncthreads();
    if (tid < 64) {
        float S = sbm[0][tid] + sbm[1][tid] + sbm[2][tid] + sbm[3][tid];
        float Q = qbm[0][tid] + qbm[1][tid] + qbm[2][tid] + qbm[3][tid];
        atomicAdd(&sums[tid], S);
        atomicAdd(&sums[64 + tid], Q);
    }
}

// Two-buffer fp32 stats via grid halves (convB / convC).
__global__ void stats2f_k(const float* __restrict__ ra, const float* __restrict__ rb,
                          float* __restrict__ sa, float* __restrict__ sb, int half) {
    const float* raw = ((int)blockIdx.x < half) ? ra : rb;
    float* sums      = ((int)blockIdx.x < half) ? sa : sb;
    int bx = ((int)blockIdx.x < half) ? (int)blockIdx.x : (int)blockIdx.x - half;
    int tid = threadIdx.x;
    int wave = tid >> 6, c = tid & 63;
    int gw = bx * 4 + wave;
    int GW = half * 4;
    float s = 0.f, q = 0.f;
    for (int r = gw; r < NC; r += GW) {
        float v = raw[(size_t)r * 64 + c];
        s += v; q += v * v;
    }
    __shared__ float sbm[4][64], qbm[4][64];
    sbm[wave][c] = s; qbm[wave][c] = q;
    __syncthreads();
    if (tid < 64) {
        float S = sbm[0][tid] + sbm[1][tid] + sbm[2][tid] + sbm[3][tid];
        float Q = qbm[0][tid] + qbm[1][tid] + qbm[2][tid] + qbm[3][tid];
        atomicAdd(&sums[tid], S);
        atomicAdd(&sums[64 + tid], Q);
    }
}

// scale = g*rsqrt(var+eps); shift = b - mean*scale  (biased var, matches jnp.var)
__global__ void finalize_k(const float* __restrict__ sums, const float* __restrict__ g,
                           const float* __restrict__ bb, float* __restrict__ scsh) {
    int c = threadIdx.x;
    if (c < 64) {
        float m = sums[c] / (float)NC;
        float v = sums[64 + c] / (float)NC - m * m;
        float sc = g[c] * rsqrtf(v + 1e-5f);
        scsh[c] = sc;
        scsh[64 + c] = bb[c] - m * sc;
    }
}

// up = bf16((leaky?)(raw) * scale + shift); pad row zeroed.
template <bool LEAKY>
__global__ void apply_f32_k(const float* __restrict__ raw, const float* __restrict__ scsh,
                            u16* __restrict__ up) {
    int idx = blockIdx.x * blockDim.x + threadIdx.x;
    if (idx >= (NC + 1) * 64) return;
    int c = idx & 63, i = idx >> 6;
    u16 o = 0;
    if (i < NC) {
        float v = raw[idx];
        if (LEAKY) v = v > 0.f ? v : 0.01f * v;
        o = f2bf(v * scsh[c] + scsh[64 + c]);
    }
    up[idx] = o;
}

__global__ void apply12f_k(const float* __restrict__ rb, const float* __restrict__ rc,
                           const float* __restrict__ s1, const float* __restrict__ s2,
                           u16* __restrict__ up) {
    int idx = blockIdx.x * blockDim.x + threadIdx.x;
    if (idx >= (NC + 1) * 64) return;
    int c = idx & 63, i = idx >> 6;
    u16 o = 0;
    if (i < NC) {
        float v = rb[idx] * s1[c] + s1[64 + c] + rc[idx] * s2[c] + s2[64 + c];
        o = f2bf(v);
    }
    up[idx] = o;
}

extern "C" void kernel_launch(void* const* d_in, const int* in_sizes, int n_in,
                              void* d_out, int out_size, void* d_ws, size_t ws_size,
                              hipStream_t stream) {
    const float* feats_x    = (const float*)d_in[0];
    const float* feats_skip = (const float*)d_in[1];
    const float* W_trans    = (const float*)d_in[2];
    const float* W1         = (const float*)d_in[3];
    const float* W2         = (const float*)d_in[4];
    const float* W_up       = (const float*)d_in[5];
    const float* g0 = (const float*)d_in[6],  *b0 = (const float*)d_in[7];
    const float* g1 = (const float*)d_in[8],  *b1 = (const float*)d_in[9];
    const float* g2 = (const float*)d_in[10], *b2 = (const float*)d_in[11];
    const int* pairs33 = (const int*)d_in[12];
    const int* pairs13 = (const int*)d_in[13];
    const int* pairs31 = (const int*)d_in[14];
    const int* pairs_up = (const int*)d_in[15];
    float* outp = (float*)d_out;   // reference output dtype: float32

    char* ws = (char*)d_ws;
    size_t off = 0;
    auto alloc = [&](size_t bytes) {
        char* p = ws + off;
        off += (bytes + 255) & ~(size_t)255;
        return p;
    };
    u16* xp       = (u16*)alloc(30720256);    // [NC+1][128] bf16; later upA + upE
    float* rawA32 = (float*)alloc(30720000);  // [NC][64] f32; later rawB32
    float* rawC32 = (float*)alloc(30720000);  // [NC][64] f32
    u16* WtA   = (u16*)alloc(27 * 128 * 64 * 2);
    u16* Wt1   = (u16*)alloc(9 * 64 * 64 * 2);
    u16* Wt2   = (u16*)alloc(9 * 64 * 64 * 2);
    u16* WtU   = (u16*)alloc(9 * 64 * 64 * 2);
    float* stats = (float*)alloc(6 * 128 * 4);
    int* meta  = (int*)alloc(1024);           // A@+0, BC@+64, U@+128
    u16* upA = xp;                               // [NC+1][64] — xp dead after sparseA
    u16* upE = (u16*)((char*)xp + 15360128);     // [NC+1][64]
    float* rawB32 = rawA32;                      // rawA32 dead after apply
    float *sums0 = stats,        *sums1 = stats + 128, *sums2 = stats + 256;
    float *scsh0 = stats + 384,  *scsh1 = stats + 512, *scsh2 = stats + 640;

    const int B = 256;
    hipMemsetAsync(stats, 0, 6 * 128 * 4, stream);

    transpose_w_k<<<(27 * 128 * 64 + 255) / 256, B, 0, stream>>>(W_trans, WtA, 27, 128);
    transpose_w_k<<<(9 * 64 * 64 + 255) / 256, B, 0, stream>>>(W1, Wt1, 9, 64);
    transpose_w_k<<<(9 * 64 * 64 + 255) / 256, B, 0, stream>>>(W2, Wt2, 9, 64);
    transpose_wup_k<<<(9 * 64 * 64 + 255) / 256, B, 0, stream>>>(W_up, WtU);

    add_pad_k<<<((NC + 1) * 32 + 255) / 256, B, 0, stream>>>(feats_x, feats_skip, xp);
    counts_k<<<1, 64, 0, stream>>>(pairs33, pairs13, pairs31, pairs_up, meta);

    // ---- conv_trans = dense identity tap (k=13) + 26 sparse taps ----
    dense_k<128, false><<<938, B, 0, stream>>>(
        xp, WtA + 13 * 128 * 64, WtA, rawA32, rawA32, NC);
    sparse_k<128, 0, 26><<<2048, B, 0, stream>>>(
        xp, pairs33, pairs33, WtA, WtA, rawA32, rawA32, meta, NC);
    stats_f32_k<true><<<240, B, 0, stream>>>(rawA32, sums0, 240);
    finalize_k<<<1, 64, 0, stream>>>(sums0, g0, b0, scsh0);
    apply_f32_k<true><<<((NC + 1) * 64 + 255) / 256, B, 0, stream>>>(rawA32, scsh0, upA);

    // ---- conv1x3 + conv3x1 = dense center taps (k=4) + 16 sparse taps ----
    dense_k<64, true><<<938, B, 0, stream>>>(
        upA, Wt1 + 4 * 64 * 64, Wt2 + 4 * 64 * 64, rawB32, rawC32, NC);
    sparse_k<64, 1, 16><<<1024, B, 0, stream>>>(
        upA, pairs13, pairs31, Wt1, Wt2, rawB32, rawC32, meta + 64, NC);
    stats2f_k<<<240, B, 0, stream>>>(rawB32, rawC32, sums1, sums2, 120);
    finalize_k<<<1, 64, 0, stream>>>(sums1, g1, b1, scsh1);
    finalize_k<<<1, 64, 0, stream>>>(sums2, g2, b2, scsh2);
    apply12f_k<<<((NC + 1) * 64 + 255) / 256, B, 0, stream>>>(rawB32, rawC32, scsh1, scsh2, upE);

    // ---- upsample = dense identity halves (slots 0/8) + 7 sparse taps ----
    dense_k<64, true><<<938, B, 0, stream>>>(
        upE, WtU, WtU + 8 * 64 * 64, outp, outp + (size_t)NC * 64, NC);
    sparse_k<64, 2, 7><<<512, B, 0, stream>>>(
        upE, pairs_up, pairs_up, WtU, WtU, outp, outp, meta + 128, NF);
}

// Round 5
// 523.420 us; speedup vs baseline: 1.0491x; 1.0491x over previous
//
#include <hip/hip_runtime.h>
#include <stdint.h>

typedef unsigned short u16;
typedef unsigned int u32;
typedef __bf16 bf16x8 __attribute__((ext_vector_type(8)));
typedef float floatx4 __attribute__((ext_vector_type(4)));

static constexpr int NC = 120000;
static constexpr int NF = 240000;

__device__ __forceinline__ float bf2f(u16 u) {
    union { u32 i; float f; } v; v.i = ((u32)u) << 16; return v.f;
}
__device__ __forceinline__ u16 f2bf(float f) {
    union { float f; u32 i; } v; v.f = f;
    u32 r = v.i + 0x7FFFu + ((v.i >> 16) & 1u);
    return (u16)(r >> 16);
}

// Bijective XCD-aware swizzle: blocks dispatch round-robin across 8 XCDs
// (xcd ~ bid%8); remap so each XCD executes a CONTIGUOUS band of output
// tiles. Row IDs of gather targets are quasi-monotone in output row (IDs
// assigned in sorted flat-coord order), so contiguous bands make the
// gather working set L2-resident per XCD.
__device__ __forceinline__ int xcd_swz(int bid, int nb) {
    int q = nb >> 3, r = nb & 7;
    int x = bid & 7, i = bid >> 3;
    return (x < r ? x * (q + 1) : r * (q + 1) + (x - r) * q) + i;
}

// xp[i] = bf16(feats_x[i] + feats_skip[i]) for i < NC rows; row NC zeroed (pad row).
__global__ void add_pad_k(const float* __restrict__ a, const float* __restrict__ b,
                          u16* __restrict__ xp) {
    int idx = blockIdx.x * blockDim.x + threadIdx.x;  // 4 elements per thread
    if (idx >= (NC + 1) * 32) return;
    uint2 vo;
    if (idx < NC * 32) {
        float4 va = ((const float4*)a)[idx];
        float4 vb = ((const float4*)b)[idx];
        vo.x = (u32)f2bf(va.x + vb.x) | ((u32)f2bf(va.y + vb.y) << 16);
        vo.y = (u32)f2bf(va.z + vb.z) | ((u32)f2bf(va.w + vb.w) << 16);
    } else {
        vo.x = vo.y = 0u;
    }
    ((uint2*)xp)[idx] = vo;
}

// Fragment-major weight layout: Wt[k][kc][nt][lane][j] = bf16(W[k][ci][co])
// with ci = kc*32 + (lane>>4)*8 + j, co = nt*16 + (lane&15).
__global__ void transpose_w_k(const float* __restrict__ W, u16* __restrict__ Wt,
                              int K, int Cin) {
    int idx = blockIdx.x * blockDim.x + threadIdx.x;
    if (idx >= K * Cin * 64) return;
    int per = Cin * 64;
    int k = idx / per, rem = idx - k * per;
    int kc = rem >> 11;             // rem / 2048
    int r2 = rem & 2047;
    int nt = r2 >> 9, lane = (r2 >> 3) & 63, j = r2 & 7;
    int ci = kc * 32 + (lane >> 4) * 8 + j;
    int co = nt * 16 + (lane & 15);
    Wt[idx] = f2bf(W[(size_t)(k * Cin + ci) * 64 + co]);
}

// Upsample slots (parity structure of k=3,s=2,p=1 inverse conv):
// slot 0 = tap 13 (even fine rows, identity map); slots 1..8 = even taps
// (odd fine rows).
__device__ __forceinline__ int upslot_to_k(int s) {
    if (s == 0) return 13;
    int e = s - 1;
    return 18 * ((e >> 2) & 1) + 6 * ((e >> 1) & 1) + 2 * (e & 1);
}
__global__ void transpose_wup_k(const float* __restrict__ W, u16* __restrict__ Wt) {
    int idx = blockIdx.x * blockDim.x + threadIdx.x;
    if (idx >= 9 * 4096) return;
    int s = idx >> 12, rem = idx & 4095;
    int kc = rem >> 11, r2 = rem & 2047;
    int nt = r2 >> 9, lane = (r2 >> 3) & 63, j = r2 & 7;
    int ci = kc * 32 + (lane >> 4) * 8 + j;
    int co = nt * 16 + (lane & 15);
    int k = upslot_to_k(s);
    Wt[idx] = f2bf(W[(size_t)(k * 64 + ci) * 64 + co]);
}

__global__ void fill_k(int* __restrict__ p, int n, int val) {
    int i = blockIdx.x * blockDim.x + threadIdx.x;
    if (i < n) p[i] = val;
}

// inv[k][out] = in  for each valid pair (out indices unique per k).
__global__ void scatter_k(const int* __restrict__ pairs, int* __restrict__ inv,
                          int npairs, int n_out) {
    int i = blockIdx.x * blockDim.x + threadIdx.x;
    if (i >= npairs) return;
    int in = pairs[2 * i], out = pairs[2 * i + 1];
    if (out < n_out) inv[(i / NC) * n_out + out] = in;
}

// Upsample scatter with 27->9 slot compaction (only 9 taps can ever be valid).
__global__ void scatter_up_k(const int* __restrict__ pairs, int* __restrict__ inv) {
    int i = blockIdx.x * blockDim.x + threadIdx.x;
    if (i >= 27 * NC) return;
    int in = pairs[2 * i], out = pairs[2 * i + 1];
    if (out >= NF) return;
    int k = i / NC;
    int a = k / 9, r = k - a * 9, b = r / 3, c = r - b * 3;
    int s;
    if (k == 13) {
        s = 0;
    } else if (((a | b | c) & 1) == 0) {
        s = 1 + (a >> 1) * 4 + (b >> 1) * 2 + (c >> 1);
    } else {
        return;                    // structurally impossible for a valid pair
    }
    inv[(size_t)s * NF + out] = in;
}

// Barrier-synced, LDS-weight-staged gather-GEMM sparse conv (gather-side:
// exclusive output writes, no atomics). Dual problem sets via grid concat;
// runtime Klive per problem. XCD-bijective bid swizzle (contiguous out-row
// band per XCD -> quasi-monotone gather targets stay L2-resident).
// Per wave: R row-tiles of 16 rows x 64 cols; A-fragments double-buffered in
// registers; row indices prefetched two taps ahead; weights double-buffered
// in LDS (staged once per block per tap).
// Grid tail: row indices clamped on inv reads, C-writes guarded (row < nr).
// MINW=2 for the Cin=128 instance: tighter bounds spill (measured round 1:
// MINW=4 -> 1GB scratch traffic, 5x slowdown).
template <int TCIN, int KMAX, int R, bool LEAKY, bool F32OUT, int MINW>
__global__ __launch_bounds__(256, MINW) void spconv_k(
    const u16* __restrict__ feats,
    const int* __restrict__ invA, const u16* __restrict__ wTA, void* __restrict__ outA,
    const int* __restrict__ invB, const u16* __restrict__ wTB, void* __restrict__ outB,
    int nb0, int n_outA, int n_outB, int kliveA, int kliveB, int nrA, int nrB) {
    constexpr int KC = TCIN / 32;
    constexpr int WFRAGS = TCIN * 64 / 8;      // bf16x8 frags per tap (1024 / 512)
    constexpr int NST = WFRAGS / 256;          // staging chunks per thread (4 / 2)
    __shared__ bf16x8 wlds[2][WFRAGS];

    const int tid = threadIdx.x;
    const int wave = tid >> 6, lane = tid & 63;
    const int l15 = lane & 15, quad = lane >> 4;
    const bool second = (int)blockIdx.x >= nb0;
    int bid = second ? (int)blockIdx.x - nb0 : (int)blockIdx.x;
    const int nb = second ? (int)gridDim.x - nb0 : nb0;
    bid = xcd_swz(bid, nb);
    const int* __restrict__ inv = second ? invB : invA;
    const u16* __restrict__ wT  = second ? wTB : wTA;
    void* __restrict__ outv     = second ? outB : outA;
    const int n_out             = second ? n_outB : n_outA;  // inv stride
    const int Klive             = second ? kliveB : kliveA;
    const int nr                = second ? nrB : nrA;        // valid row count

    const int blockrow = bid * (R * 64);
    const int base = blockrow + wave * 16 + l15;

    int rowix[R];
#pragma unroll
    for (int t = 0; t < R; ++t) rowix[t] = min(base + t * 64, nr - 1);

    floatx4 acc[R][4];
#pragma unroll
    for (int t = 0; t < R; ++t)
#pragma unroll
        for (int nt = 0; nt < 4; ++nt) acc[t][nt] = (floatx4)(0.0f);

    int rc[R], rn[R];
#pragma unroll
    for (int t = 0; t < R; ++t) rc[t] = inv[rowix[t]];
#pragma unroll
    for (int t = 0; t < R; ++t) rn[t] = inv[n_out + rowix[t]];

    // stage weights for tap 0 into wlds[0] (cooperative, coalesced)
    {
        const bf16x8* wsrc = (const bf16x8*)wT + tid;
#pragma unroll
        for (int s = 0; s < NST; ++s) wlds[0][tid + s * 256] = wsrc[s * 256];
    }

    bf16x8 abuf[2][R][KC];
    // prologue: gather A for tap 0 (live tiles only)
#pragma unroll
    for (int t = 0; t < R; ++t) {
        if (__any(rc[t] != NC)) {
            const u16* ap = feats + (size_t)rc[t] * TCIN + quad * 8;
#pragma unroll
            for (int kc = 0; kc < KC; ++kc) abuf[0][t][kc] = *(const bf16x8*)(ap + kc * 32);
        }
    }
    __syncthreads();

#pragma unroll
    for (int k = 0; k < KMAX; ++k) {
        if (k < Klive) {
            const int cur = k & 1, nxt = cur ^ 1;
            // stage weights for tap k+1 into the other LDS buffer
            if (k + 1 < Klive) {
                const bf16x8* wsrc = (const bf16x8*)(wT + (size_t)(k + 1) * (64 * TCIN)) + tid;
                bf16x8 st[NST];
#pragma unroll
                for (int s = 0; s < NST; ++s) st[s] = wsrc[s * 256];
#pragma unroll
                for (int s = 0; s < NST; ++s) wlds[nxt][tid + s * 256] = st[s];
            }
            int rf[R];
#pragma unroll
            for (int t = 0; t < R; ++t) rf[t] = NC;
            if (k + 2 < Klive) {
                const int* invf = inv + (size_t)(k + 2) * n_out;
#pragma unroll
                for (int t = 0; t < R; ++t) rf[t] = invf[rowix[t]];
            }
            bool lv[R], any = false;
#pragma unroll
            for (int t = 0; t < R; ++t) { lv[t] = __any(rc[t] != NC); any = any || lv[t]; }
            // prefetch A for tap k+1 into the other register buffer
            if (k + 1 < Klive) {
#pragma unroll
                for (int t = 0; t < R; ++t) {
                    if (__any(rn[t] != NC)) {
                        const u16* ap = feats + (size_t)rn[t] * TCIN + quad * 8;
#pragma unroll
                        for (int kc = 0; kc < KC; ++kc)
                            abuf[nxt][t][kc] = *(const bf16x8*)(ap + kc * 32);
                    }
                }
            }
            if (any) {
                bf16x8 b[KC][4];
#pragma unroll
                for (int kc = 0; kc < KC; ++kc)
#pragma unroll
                    for (int nt = 0; nt < 4; ++nt)
                        b[kc][nt] = wlds[cur][(kc * 4 + nt) * 64 + lane];
#pragma unroll
                for (int t = 0; t < R; ++t) {
                    if (lv[t]) {
#pragma unroll
                        for (int kc = 0; kc < KC; ++kc)
#pragma unroll
                            for (int nt = 0; nt < 4; ++nt)
                                acc[t][nt] = __builtin_amdgcn_mfma_f32_16x16x32_bf16(
                                    abuf[cur][t][kc], b[kc][nt], acc[t][nt], 0, 0, 0);
                    }
                }
            }
            __syncthreads();
#pragma unroll
            for (int t = 0; t < R; ++t) { rc[t] = rn[t]; rn[t] = rf[t]; }
        }
    }
    // C/D layout: col = lane&15, row = quad*4 + reg
#pragma unroll
    for (int t = 0; t < R; ++t) {
#pragma unroll
        for (int nt = 0; nt < 4; ++nt) {
#pragma unroll
            for (int r = 0; r < 4; ++r) {
                float v = acc[t][nt][r];
                if (LEAKY) v = v > 0.f ? v : 0.01f * v;
                int row = blockrow + t * 64 + wave * 16 + quad * 4 + r;
                if (row < nr) {
                    size_t oi = (size_t)row * 64 + nt * 16 + l15;
                    if (F32OUT) ((float*)outv)[oi] = v;
                    else        ((u16*)outv)[oi] = f2bf(v);
                }
            }
        }
    }
}

// Per-channel sum/sumsq over one [NC][64] bf16 buffer, fp32 accum.
__global__ void stats1_k(const u16* __restrict__ raw, float* __restrict__ sums,
                         int nblk) {
    int tid = threadIdx.x;
    int wave = tid >> 6, c = tid & 63;
    int gw = (int)blockIdx.x * 4 + wave;
    int GW = nblk * 4;
    float s = 0.f, q = 0.f;
    for (int r = gw; r < NC; r += GW) {
        float v = bf2f(raw[(size_t)r * 64 + c]);
        s += v; q += v * v;
    }
    __shared__ float sbm[4][64], qbm[4][64];
    sbm[wave][c] = s; qbm[wave][c] = q;
    __syncthreads();
    if (tid < 64) {
        float S = sbm[0][tid] + sbm[1][tid] + sbm[2][tid] + sbm[3][tid];
        float Q = qbm[0][tid] + qbm[1][tid] + qbm[2][tid] + qbm[3][tid];
        atomicAdd(&sums[tid], S);
        atomicAdd(&sums[64 + tid], Q);
    }
}

// Per-channel sum/sumsq over two [NC][64] bf16 buffers (grid halves), fp32 accum.
__global__ void stats2_k(const u16* __restrict__ ra, const u16* __restrict__ rb,
                         float* __restrict__ sa, float* __restrict__ sb, int half) {
    const u16* raw = ((int)blockIdx.x < half) ? ra : rb;
    float* sums    = ((int)blockIdx.x < half) ? sa : sb;
    int bx = ((int)blockIdx.x < half) ? (int)blockIdx.x : (int)blockIdx.x - half;
    int tid = threadIdx.x;
    int wave = tid >> 6, c = tid & 63;
    int gw = bx * 4 + wave;
    int GW = half * 4;
    float s = 0.f, q = 0.f;
    for (int r = gw; r < NC; r += GW) {
        float v = bf2f(raw[(size_t)r * 64 + c]);
        s += v; q += v * v;
    }
    __shared__ float sbm[4][64], qbm[4][64];
    sbm[wave][c] = s; qbm[wave][c] = q;
    __syncthreads();
    if (tid < 64) {
        float S = sbm[0][tid] + sbm[1][tid] + sbm[2][tid] + sbm[3][tid];
        float Q = qbm[0][tid] + qbm[1][tid] + qbm[2][tid] + qbm[3][tid];
        atomicAdd(&sums[tid], S);
        atomicAdd(&sums[64 + tid], Q);
    }
}

// scale = g*rsqrt(var+eps); shift = b - mean*scale  (biased var, matches jnp.var)
__global__ void finalize_k(const float* __restrict__ sums, const float* __restrict__ g,
                           const float* __restrict__ bb, float* __restrict__ scsh) {
    int c = threadIdx.x;
    if (c < 64) {
        float m = sums[c] / (float)NC;
        float v = sums[64 + c] / (float)NC - m * m;
        float sc = g[c] * rsqrtf(v + 1e-5f);
        scsh[c] = sc;
        scsh[64 + c] = bb[c] - m * sc;
    }
}

__global__ void apply0_k(const u16* __restrict__ raw, const float* __restrict__ scsh,
                         u16* __restrict__ up) {
    int idx = blockIdx.x * blockDim.x + threadIdx.x;
    if (idx >= (NC + 1) * 64) return;
    int c = idx & 63, i = idx >> 6;
    up[idx] = (i < NC) ? f2bf(bf2f(raw[idx]) * scsh[c] + scsh[64 + c]) : (u16)0;
}

__global__ void apply12_k(const u16* __restrict__ rb, const u16* __restrict__ rc,
                          const float* __restrict__ s1, const float* __restrict__ s2,
                          u16* __restrict__ up) {
    int idx = blockIdx.x * blockDim.x + threadIdx.x;
    if (idx >= (NC + 1) * 64) return;
    int c = idx & 63, i = idx >> 6;
    float v = bf2f(rb[idx]) * s1[c] + s1[64 + c] + bf2f(rc[idx]) * s2[c] + s2[64 + c];
    up[idx] = (i < NC) ? f2bf(v) : (u16)0;
}

extern "C" void kernel_launch(void* const* d_in, const int* in_sizes, int n_in,
                              void* d_out, int out_size, void* d_ws, size_t ws_size,
                              hipStream_t stream) {
    const float* feats_x    = (const float*)d_in[0];
    const float* feats_skip = (const float*)d_in[1];
    const float* W_trans    = (const float*)d_in[2];
    const float* W1         = (const float*)d_in[3];
    const float* W2         = (const float*)d_in[4];
    const float* W_up       = (const float*)d_in[5];
    const float* g0 = (const float*)d_in[6],  *b0 = (const float*)d_in[7];
    const float* g1 = (const float*)d_in[8],  *b1 = (const float*)d_in[9];
    const float* g2 = (const float*)d_in[10], *b2 = (const float*)d_in[11];
    const int* pairs33 = (const int*)d_in[12];
    const int* pairs13 = (const int*)d_in[13];
    const int* pairs31 = (const int*)d_in[14];
    const int* pairs_up = (const int*)d_in[15];
    float* outp = (float*)d_out;   // reference output dtype: float32

    char* ws = (char*)d_ws;
    size_t off = 0;
    auto alloc = [&](size_t bytes) {
        char* p = ws + off;
        off += (bytes + 255) & ~(size_t)255;
        return p;
    };
    u16* xp    = (u16*)alloc(30720256);   // [NC+1][128] bf16; later overlaid by inv_up
    int* inv33 = (int*)alloc(12960000);   // [27][NC]
    int* inv13 = (int*)alloc(4320000);    // [9][NC]  (contiguous with inv33)
    int* inv31 = (int*)alloc(4320000);    // [9][NC]  (contiguous)
    u16* rawA  = (u16*)alloc(15360000);   // [NC][64] bf16 (leaky pre-applied); later rawB
    u16* rawC  = (u16*)alloc(15360000);   // [NC][64]
    u16* upA   = (u16*)alloc(15360128);   // [NC+1][64]
    u16* WtA   = (u16*)alloc(27 * 128 * 64 * 2);
    u16* Wt1   = (u16*)alloc(9 * 64 * 64 * 2);
    u16* Wt2   = (u16*)alloc(9 * 64 * 64 * 2);
    u16* WtU   = (u16*)alloc(9 * 64 * 64 * 2);   // 9 parity-valid slots
    float* stats = (float*)alloc(6 * 128 * 4);
    int* inv_up = (int*)xp;               // [9][NF] = 8.64MB — xp dead after convA
    u16* rawB = rawA;                     // rawA dead after apply0
    u16* upE  = (u16*)inv33;              // inv33+inv13 dead after convBC
    float *sums0 = stats,        *sums1 = stats + 128, *sums2 = stats + 256;
    float *scsh0 = stats + 384,  *scsh1 = stats + 512, *scsh2 = stats + 640;

    const int B = 256;
    hipMemsetAsync(stats, 0, 6 * 128 * 4, stream);

    transpose_w_k<<<(27 * 128 * 64 + 255) / 256, B, 0, stream>>>(W_trans, WtA, 27, 128);
    transpose_w_k<<<(9 * 64 * 64 + 255) / 256, B, 0, stream>>>(W1, Wt1, 9, 64);
    transpose_w_k<<<(9 * 64 * 64 + 255) / 256, B, 0, stream>>>(W2, Wt2, 9, 64);
    transpose_wup_k<<<(9 * 64 * 64 + 255) / 256, B, 0, stream>>>(W_up, WtU);

    add_pad_k<<<((NC + 1) * 32 + 255) / 256, B, 0, stream>>>(feats_x, feats_skip, xp);

    // inv33/inv13/inv31 are contiguous: one fill over 45*NC ints
    fill_k<<<(45 * NC + 255) / 256, B, 0, stream>>>(inv33, 45 * NC, NC);
    scatter_k<<<(27 * NC + 255) / 256, B, 0, stream>>>(pairs33, inv33, 27 * NC, NC);
    scatter_k<<<(9 * NC + 255) / 256, B, 0, stream>>>(pairs13, inv13, 9 * NC, NC);
    scatter_k<<<(9 * NC + 255) / 256, B, 0, stream>>>(pairs31, inv31, 9 * NC, NC);

    // conv_trans: 27 taps, Cin=128, leaky fused into bf16 writer. 938 blocks
    // x 128 rows, XCD-swizzled for gather L2 locality.
    spconv_k<128, 27, 2, true, false, 2><<<938, B, 0, stream>>>(
        xp, inv33, WtA, rawA, inv33, WtA, rawA, 938, NC, NC, 27, 27, NC, NC);
    stats1_k<<<240, B, 0, stream>>>(rawA, sums0, 240);
    finalize_k<<<1, 64, 0, stream>>>(sums0, g0, b0, scsh0);
    apply0_k<<<((NC + 1) * 64 + 255) / 256, B, 0, stream>>>(rawA, scsh0, upA);

    // xp dead — build compacted 9-slot upsample inverse map in its region
    fill_k<<<(9 * NF + 255) / 256, B, 0, stream>>>(inv_up, 9 * NF, NC);
    scatter_up_k<<<(27 * NC + 255) / 256, B, 0, stream>>>(pairs_up, inv_up);

    // conv1x3 + conv3x1 fused via grid concat: 938 + 938 blocks
    spconv_k<64, 9, 2, false, false, 3><<<1876, B, 0, stream>>>(
        upA, inv13, Wt1, rawB, inv31, Wt2, rawC, 938, NC, NC, 9, 9, NC, NC);
    stats2_k<<<240, B, 0, stream>>>(rawB, rawC, sums1, sums2, 120);
    finalize_k<<<1, 64, 0, stream>>>(sums1, g1, b1, scsh1);
    finalize_k<<<1, 64, 0, stream>>>(sums2, g2, b2, scsh2);

    apply12_k<<<((NC + 1) * 64 + 255) / 256, B, 0, stream>>>(rawB, rawC, scsh1, scsh2, upE);

    // upsample inverse conv -> d_out (float32), regime-split via dual problem:
    //   A: blocks 0-937, fine rows < NC (even parity): 1 tap (slot 0 = tap 13,
    //      identity gather).
    //   B: blocks 938-1875, fine rows >= NC (odd parity): 8 taps (slots 1-8),
    //      inv/out offset by NC.
    spconv_k<64, 8, 2, false, true, 3><<<1876, B, 0, stream>>>(
        upE, inv_up, WtU, outp,
        inv_up + (size_t)NF + NC, WtU + 64 * 64, (void*)(outp + (size_t)NC * 64),
        938, NF, NF, 1, 8, NC, NC);
}

// Round 6
// 516.798 us; speedup vs baseline: 1.0626x; 1.0128x over previous
//
#include <hip/hip_runtime.h>
#include <stdint.h>

typedef unsigned short u16;
typedef unsigned int u32;
typedef __bf16 bf16x8 __attribute__((ext_vector_type(8)));
typedef float floatx4 __attribute__((ext_vector_type(4)));

static constexpr int NC = 120000;
static constexpr int NF = 240000;

__device__ __forceinline__ float bf2f(u16 u) {
    union { u32 i; float f; } v; v.i = ((u32)u) << 16; return v.f;
}
__device__ __forceinline__ u16 f2bf(float f) {
    union { float f; u32 i; } v; v.f = f;
    u32 r = v.i + 0x7FFFu + ((v.i >> 16) & 1u);
    return (u16)(r >> 16);
}

// Bijective XCD-aware swizzle: contiguous block band per XCD (gather targets
// are quasi-monotone in output row, so bands keep the working set L2-local).
__device__ __forceinline__ int xcd_swz(int bid, int nb) {
    int q = nb >> 3, r = nb & 7;
    int x = bid & 7, i = bid >> 3;
    return (x < r ? x * (q + 1) : r * (q + 1) + (x - r) * q) + i;
}

// xp[i] = bf16(feats_x[i] + feats_skip[i]) for i < NC rows; row NC zeroed (pad row).
__global__ void add_pad_k(const float* __restrict__ a, const float* __restrict__ b,
                          u16* __restrict__ xp) {
    int idx = blockIdx.x * blockDim.x + threadIdx.x;  // 4 elements per thread
    if (idx >= (NC + 1) * 32) return;
    uint2 vo;
    if (idx < NC * 32) {
        float4 va = ((const float4*)a)[idx];
        float4 vb = ((const float4*)b)[idx];
        vo.x = (u32)f2bf(va.x + vb.x) | ((u32)f2bf(va.y + vb.y) << 16);
        vo.y = (u32)f2bf(va.z + vb.z) | ((u32)f2bf(va.w + vb.w) << 16);
    } else {
        vo.x = vo.y = 0u;
    }
    ((uint2*)xp)[idx] = vo;
}

// Fragment-major weight layout: Wt[k][kc][nt][lane][j] = bf16(W[k][ci][co])
// with ci = kc*32 + (lane>>4)*8 + j, co = nt*16 + (lane&15).
__global__ void transpose_w_k(const float* __restrict__ W, u16* __restrict__ Wt,
                              int K, int Cin) {
    int idx = blockIdx.x * blockDim.x + threadIdx.x;
    if (idx >= K * Cin * 64) return;
    int per = Cin * 64;
    int k = idx / per, rem = idx - k * per;
    int kc = rem >> 11;             // rem / 2048
    int r2 = rem & 2047;
    int nt = r2 >> 9, lane = (r2 >> 3) & 63, j = r2 & 7;
    int ci = kc * 32 + (lane >> 4) * 8 + j;
    int co = nt * 16 + (lane & 15);
    Wt[idx] = f2bf(W[(size_t)(k * Cin + ci) * 64 + co]);
}

// Upsample slots (parity structure of k=3,s=2,p=1 inverse conv):
// slot 0 = tap 13 (even fine rows, identity map); slots 1..8 = even taps
// (odd fine rows).
__device__ __forceinline__ int upslot_to_k(int s) {
    if (s == 0) return 13;
    int e = s - 1;
    return 18 * ((e >> 2) & 1) + 6 * ((e >> 1) & 1) + 2 * (e & 1);
}
__global__ void transpose_wup_k(const float* __restrict__ W, u16* __restrict__ Wt) {
    int idx = blockIdx.x * blockDim.x + threadIdx.x;
    if (idx >= 9 * 4096) return;
    int s = idx >> 12, rem = idx & 4095;
    int kc = rem >> 11, r2 = rem & 2047;
    int nt = r2 >> 9, lane = (r2 >> 3) & 63, j = r2 & 7;
    int ci = kc * 32 + (lane >> 4) * 8 + j;
    int co = nt * 16 + (lane & 15);
    int k = upslot_to_k(s);
    Wt[idx] = f2bf(W[(size_t)(k * 64 + ci) * 64 + co]);
}

__global__ void fill_k(int* __restrict__ p, int n, int val) {
    int i = blockIdx.x * blockDim.x + threadIdx.x;
    if (i < n) p[i] = val;
}

// inv[k][out] = in  for each valid pair (out indices unique per k).
__global__ void scatter_k(const int* __restrict__ pairs, int* __restrict__ inv,
                          int npairs, int n_out) {
    int i = blockIdx.x * blockDim.x + threadIdx.x;
    if (i >= npairs) return;
    int in = pairs[2 * i], out = pairs[2 * i + 1];
    if (out < n_out) inv[(i / NC) * n_out + out] = in;
}

// Upsample scatter with 27->9 slot compaction (only 9 taps can ever be valid).
__global__ void scatter_up_k(const int* __restrict__ pairs, int* __restrict__ inv) {
    int i = blockIdx.x * blockDim.x + threadIdx.x;
    if (i >= 27 * NC) return;
    int in = pairs[2 * i], out = pairs[2 * i + 1];
    if (out >= NF) return;
    int k = i / NC;
    int a = k / 9, r = k - a * 9, b = r / 3, c = r - b * 3;
    int s;
    if (k == 13) {
        s = 0;
    } else if (((a | b | c) & 1) == 0) {
        s = 1 + (a >> 1) * 4 + (b >> 1) * 2 + (c >> 1);
    } else {
        return;                    // structurally impossible for a valid pair
    }
    inv[(size_t)s * NF + out] = in;
}

// Barrier-synced, LDS-weight-staged gather-GEMM sparse conv (gather-side:
// exclusive output writes, no atomics). Dual problem sets via grid concat;
// runtime Klive per problem. XCD-bijective bid swizzle.
//
// KEY (round 6): the A-gather is EXEC-MASKED per lane. Dummy lanes (row==NC,
// ~75-86% of lanes on 12%-dense sparse taps) previously issued pad-row loads
// that consumed L1/TA request slots -- per block-tap the issued A bytes (32KB)
// + B staging (16KB) cost ~750 L1-cy vs ~155 cy of MFMA, capping MfmaUtil at
// ~21% (measured 19-20% across four structural variants). Masked lanes issue
// no requests; their fragments are zeroed in registers (pad row is zeros, so
// results are bit-identical).
//
// Per wave: R row-tiles of 16 rows x 64 cols; A-fragments double-buffered in
// registers; row indices prefetched two taps ahead; weights double-buffered
// in LDS (staged once per block per tap). Grid tail: inv reads clamped,
// C-writes guarded. MINW=2 for the Cin=128 instance (tighter bounds spill:
// measured round 1, MINW=4 -> 1GB scratch traffic).
template <int TCIN, int KMAX, int R, bool LEAKY, bool F32OUT, int MINW>
__global__ __launch_bounds__(256, MINW) void spconv_k(
    const u16* __restrict__ feats,
    const int* __restrict__ invA, const u16* __restrict__ wTA, void* __restrict__ outA,
    const int* __restrict__ invB, const u16* __restrict__ wTB, void* __restrict__ outB,
    int nb0, int n_outA, int n_outB, int kliveA, int kliveB, int nrA, int nrB) {
    constexpr int KC = TCIN / 32;
    constexpr int WFRAGS = TCIN * 64 / 8;      // bf16x8 frags per tap (1024 / 512)
    constexpr int NST = WFRAGS / 256;          // staging chunks per thread (4 / 2)
    __shared__ bf16x8 wlds[2][WFRAGS];

    const int tid = threadIdx.x;
    const int wave = tid >> 6, lane = tid & 63;
    const int l15 = lane & 15, quad = lane >> 4;
    const bool second = (int)blockIdx.x >= nb0;
    int bid = second ? (int)blockIdx.x - nb0 : (int)blockIdx.x;
    const int nb = second ? (int)gridDim.x - nb0 : nb0;
    bid = xcd_swz(bid, nb);
    const int* __restrict__ inv = second ? invB : invA;
    const u16* __restrict__ wT  = second ? wTB : wTA;
    void* __restrict__ outv     = second ? outB : outA;
    const int n_out             = second ? n_outB : n_outA;  // inv stride
    const int Klive             = second ? kliveB : kliveA;
    const int nr                = second ? nrB : nrA;        // valid row count

    const int blockrow = bid * (R * 64);
    const int base = blockrow + wave * 16 + l15;
    const bf16x8 ZFRAG = {};

    int rowix[R];
#pragma unroll
    for (int t = 0; t < R; ++t) rowix[t] = min(base + t * 64, nr - 1);

    floatx4 acc[R][4];
#pragma unroll
    for (int t = 0; t < R; ++t)
#pragma unroll
        for (int nt = 0; nt < 4; ++nt) acc[t][nt] = (floatx4)(0.0f);

    int rc[R], rn[R];
#pragma unroll
    for (int t = 0; t < R; ++t) rc[t] = inv[rowix[t]];
#pragma unroll
    for (int t = 0; t < R; ++t) rn[t] = inv[n_out + rowix[t]];

    // stage weights for tap 0 into wlds[0] (cooperative, coalesced)
    {
        const bf16x8* wsrc = (const bf16x8*)wT + tid;
#pragma unroll
        for (int s = 0; s < NST; ++s) wlds[0][tid + s * 256] = wsrc[s * 256];
    }

    bf16x8 abuf[2][R][KC];
    // prologue: exec-masked gather of A for tap 0
#pragma unroll
    for (int t = 0; t < R; ++t) {
        if (rc[t] != NC) {
            const u16* ap = feats + (size_t)rc[t] * TCIN + quad * 8;
#pragma unroll
            for (int kc = 0; kc < KC; ++kc) abuf[0][t][kc] = *(const bf16x8*)(ap + kc * 32);
        } else {
#pragma unroll
            for (int kc = 0; kc < KC; ++kc) abuf[0][t][kc] = ZFRAG;
        }
    }
    __syncthreads();

#pragma unroll
    for (int k = 0; k < KMAX; ++k) {
        if (k < Klive) {
            const int cur = k & 1, nxt = cur ^ 1;
            // stage weights for tap k+1 into the other LDS buffer
            if (k + 1 < Klive) {
                const bf16x8* wsrc = (const bf16x8*)(wT + (size_t)(k + 1) * (64 * TCIN)) + tid;
                bf16x8 st[NST];
#pragma unroll
                for (int s = 0; s < NST; ++s) st[s] = wsrc[s * 256];
#pragma unroll
                for (int s = 0; s < NST; ++s) wlds[nxt][tid + s * 256] = st[s];
            }
            int rf[R];
#pragma unroll
            for (int t = 0; t < R; ++t) rf[t] = NC;
            if (k + 2 < Klive) {
                const int* invf = inv + (size_t)(k + 2) * n_out;
#pragma unroll
                for (int t = 0; t < R; ++t) rf[t] = invf[rowix[t]];
            }
            bool lv[R], any = false;
#pragma unroll
            for (int t = 0; t < R; ++t) { lv[t] = __any(rc[t] != NC); any = any || lv[t]; }
            // exec-masked prefetch of A for tap k+1 into the other register buffer
            if (k + 1 < Klive) {
#pragma unroll
                for (int t = 0; t < R; ++t) {
                    if (rn[t] != NC) {
                        const u16* ap = feats + (size_t)rn[t] * TCIN + quad * 8;
#pragma unroll
                        for (int kc = 0; kc < KC; ++kc)
                            abuf[nxt][t][kc] = *(const bf16x8*)(ap + kc * 32);
                    } else {
#pragma unroll
                        for (int kc = 0; kc < KC; ++kc) abuf[nxt][t][kc] = ZFRAG;
                    }
                }
            }
            if (any) {
                bf16x8 b[KC][4];
#pragma unroll
                for (int kc = 0; kc < KC; ++kc)
#pragma unroll
                    for (int nt = 0; nt < 4; ++nt)
                        b[kc][nt] = wlds[cur][(kc * 4 + nt) * 64 + lane];
#pragma unroll
                for (int t = 0; t < R; ++t) {
                    if (lv[t]) {
#pragma unroll
                        for (int kc = 0; kc < KC; ++kc)
#pragma unroll
                            for (int nt = 0; nt < 4; ++nt)
                                acc[t][nt] = __builtin_amdgcn_mfma_f32_16x16x32_bf16(
                                    abuf[cur][t][kc], b[kc][nt], acc[t][nt], 0, 0, 0);
                    }
                }
            }
            __syncthreads();
#pragma unroll
            for (int t = 0; t < R; ++t) { rc[t] = rn[t]; rn[t] = rf[t]; }
        }
    }
    // C/D layout: col = lane&15, row = quad*4 + reg
#pragma unroll
    for (int t = 0; t < R; ++t) {
#pragma unroll
        for (int nt = 0; nt < 4; ++nt) {
#pragma unroll
            for (int r = 0; r < 4; ++r) {
                float v = acc[t][nt][r];
                if (LEAKY) v = v > 0.f ? v : 0.01f * v;
                int row = blockrow + t * 64 + wave * 16 + quad * 4 + r;
                if (row < nr) {
                    size_t oi = (size_t)row * 64 + nt * 16 + l15;
                    if (F32OUT) ((float*)outv)[oi] = v;
                    else        ((u16*)outv)[oi] = f2bf(v);
                }
            }
        }
    }
}

// Per-channel sum/sumsq over one [NC][64] bf16 buffer, fp32 accum.
__global__ void stats1_k(const u16* __restrict__ raw, float* __restrict__ sums,
                         int nblk) {
    int tid = threadIdx.x;
    int wave = tid >> 6, c = tid & 63;
    int gw = (int)blockIdx.x * 4 + wave;
    int GW = nblk * 4;
    float s = 0.f, q = 0.f;
    for (int r = gw; r < NC; r += GW) {
        float v = bf2f(raw[(size_t)r * 64 + c]);
        s += v; q += v * v;
    }
    __shared__ float sbm[4][64], qbm[4][64];
    sbm[wave][c] = s; qbm[wave][c] = q;
    __syncthreads();
    if (tid < 64) {
        float S = sbm[0][tid] + sbm[1][tid] + sbm[2][tid] + sbm[3][tid];
        float Q = qbm[0][tid] + qbm[1][tid] + qbm[2][tid] + qbm[3][tid];
        atomicAdd(&sums[tid], S);
        atomicAdd(&sums[64 + tid], Q);
    }
}

// Per-channel sum/sumsq over two [NC][64] bf16 buffers (grid halves), fp32 accum.
__global__ void stats2_k(const u16* __restrict__ ra, const u16* __restrict__ rb,
                         float* __restrict__ sa, float* __restrict__ sb, int half) {
    const u16* raw = ((int)blockIdx.x < half) ? ra : rb;
    float* sums    = ((int)blockIdx.x < half) ? sa : sb;
    int bx = ((int)blockIdx.x < half) ? (int)blockIdx.x : (int)blockIdx.x - half;
    int tid = threadIdx.x;
    int wave = tid >> 6, c = tid & 63;
    int gw = bx * 4 + wave;
    int GW = half * 4;
    float s = 0.f, q = 0.f;
    for (int r = gw; r < NC; r += GW) {
        float v = bf2f(raw[(size_t)r * 64 + c]);
        s += v; q += v * v;
    }
    __shared__ float sbm[4][64], qbm[4][64];
    sbm[wave][c] = s; qbm[wave][c] = q;
    __syncthreads();
    if (tid < 64) {
        float S = sbm[0][tid] + sbm[1][tid] + sbm[2][tid] + sbm[3][tid];
        float Q = qbm[0][tid] + qbm[1][tid] + qbm[2][tid] + qbm[3][tid];
        atomicAdd(&sums[tid], S);
        atomicAdd(&sums[64 + tid], Q);
    }
}

// scale = g*rsqrt(var+eps); shift = b - mean*scale  (biased var, matches jnp.var)
__global__ void finalize_k(const float* __restrict__ sums, const float* __restrict__ g,
                           const float* __restrict__ bb, float* __restrict__ scsh) {
    int c = threadIdx.x;
    if (c < 64) {
        float m = sums[c] / (float)NC;
        float v = sums[64 + c] / (float)NC - m * m;
        float sc = g[c] * rsqrtf(v + 1e-5f);
        scsh[c] = sc;
        scsh[64 + c] = bb[c] - m * sc;
    }
}

__global__ void apply0_k(const u16* __restrict__ raw, const float* __restrict__ scsh,
                         u16* __restrict__ up) {
    int idx = blockIdx.x * blockDim.x + threadIdx.x;
    if (idx >= (NC + 1) * 64) return;
    int c = idx & 63, i = idx >> 6;
    up[idx] = (i < NC) ? f2bf(bf2f(raw[idx]) * scsh[c] + scsh[64 + c]) : (u16)0;
}

__global__ void apply12_k(const u16* __restrict__ rb, const u16* __restrict__ rc,
                          const float* __restrict__ s1, const float* __restrict__ s2,
                          u16* __restrict__ up) {
    int idx = blockIdx.x * blockDim.x + threadIdx.x;
    if (idx >= (NC + 1) * 64) return;
    int c = idx & 63, i = idx >> 6;
    float v = bf2f(rb[idx]) * s1[c] + s1[64 + c] + bf2f(rc[idx]) * s2[c] + s2[64 + c];
    up[idx] = (i < NC) ? f2bf(v) : (u16)0;
}

extern "C" void kernel_launch(void* const* d_in, const int* in_sizes, int n_in,
                              void* d_out, int out_size, void* d_ws, size_t ws_size,
                              hipStream_t stream) {
    const float* feats_x    = (const float*)d_in[0];
    const float* feats_skip = (const float*)d_in[1];
    const float* W_trans    = (const float*)d_in[2];
    const float* W1         = (const float*)d_in[3];
    const float* W2         = (const float*)d_in[4];
    const float* W_up       = (const float*)d_in[5];
    const float* g0 = (const float*)d_in[6],  *b0 = (const float*)d_in[7];
    const float* g1 = (const float*)d_in[8],  *b1 = (const float*)d_in[9];
    const float* g2 = (const float*)d_in[10], *b2 = (const float*)d_in[11];
    const int* pairs33 = (const int*)d_in[12];
    const int* pairs13 = (const int*)d_in[13];
    const int* pairs31 = (const int*)d_in[14];
    const int* pairs_up = (const int*)d_in[15];
    float* outp = (float*)d_out;   // reference output dtype: float32

    char* ws = (char*)d_ws;
    size_t off = 0;
    auto alloc = [&](size_t bytes) {
        char* p = ws + off;
        off += (bytes + 255) & ~(size_t)255;
        return p;
    };
    u16* xp    = (u16*)alloc(30720256);   // [NC+1][128] bf16; later overlaid by inv_up
    int* inv33 = (int*)alloc(12960000);   // [27][NC]
    int* inv13 = (int*)alloc(4320000);    // [9][NC]  (contiguous with inv33)
    int* inv31 = (int*)alloc(4320000);    // [9][NC]  (contiguous)
    u16* rawA  = (u16*)alloc(15360000);   // [NC][64] bf16 (leaky pre-applied); later rawB
    u16* rawC  = (u16*)alloc(15360000);   // [NC][64]
    u16* upA   = (u16*)alloc(15360128);   // [NC+1][64]
    u16* WtA   = (u16*)alloc(27 * 128 * 64 * 2);
    u16* Wt1   = (u16*)alloc(9 * 64 * 64 * 2);
    u16* Wt2   = (u16*)alloc(9 * 64 * 64 * 2);
    u16* WtU   = (u16*)alloc(9 * 64 * 64 * 2);   // 9 parity-valid slots
    float* stats = (float*)alloc(6 * 128 * 4);
    int* inv_up = (int*)xp;               // [9][NF] = 8.64MB — xp dead after convA
    u16* rawB = rawA;                     // rawA dead after apply0
    u16* upE  = (u16*)inv33;              // inv33+inv13 dead after convBC
    float *sums0 = stats,        *sums1 = stats + 128, *sums2 = stats + 256;
    float *scsh0 = stats + 384,  *scsh1 = stats + 512, *scsh2 = stats + 640;

    const int B = 256;
    hipMemsetAsync(stats, 0, 6 * 128 * 4, stream);

    transpose_w_k<<<(27 * 128 * 64 + 255) / 256, B, 0, stream>>>(W_trans, WtA, 27, 128);
    transpose_w_k<<<(9 * 64 * 64 + 255) / 256, B, 0, stream>>>(W1, Wt1, 9, 64);
    transpose_w_k<<<(9 * 64 * 64 + 255) / 256, B, 0, stream>>>(W2, Wt2, 9, 64);
    transpose_wup_k<<<(9 * 64 * 64 + 255) / 256, B, 0, stream>>>(W_up, WtU);

    add_pad_k<<<((NC + 1) * 32 + 255) / 256, B, 0, stream>>>(feats_x, feats_skip, xp);

    // inv33/inv13/inv31 are contiguous: one fill over 45*NC ints
    fill_k<<<(45 * NC + 255) / 256, B, 0, stream>>>(inv33, 45 * NC, NC);
    scatter_k<<<(27 * NC + 255) / 256, B, 0, stream>>>(pairs33, inv33, 27 * NC, NC);
    scatter_k<<<(9 * NC + 255) / 256, B, 0, stream>>>(pairs13, inv13, 9 * NC, NC);
    scatter_k<<<(9 * NC + 255) / 256, B, 0, stream>>>(pairs31, inv31, 9 * NC, NC);

    // conv_trans: 27 taps, Cin=128, leaky fused into bf16 writer. 938 blocks
    // x 128 rows, XCD-swizzled, exec-masked gather.
    spconv_k<128, 27, 2, true, false, 2><<<938, B, 0, stream>>>(
        xp, inv33, WtA, rawA, inv33, WtA, rawA, 938, NC, NC, 27, 27, NC, NC);
    stats1_k<<<240, B, 0, stream>>>(rawA, sums0, 240);
    finalize_k<<<1, 64, 0, stream>>>(sums0, g0, b0, scsh0);
    apply0_k<<<((NC + 1) * 64 + 255) / 256, B, 0, stream>>>(rawA, scsh0, upA);

    // xp dead — build compacted 9-slot upsample inverse map in its region
    fill_k<<<(9 * NF + 255) / 256, B, 0, stream>>>(inv_up, 9 * NF, NC);
    scatter_up_k<<<(27 * NC + 255) / 256, B, 0, stream>>>(pairs_up, inv_up);

    // conv1x3 + conv3x1 fused via grid concat: 938 + 938 blocks
    spconv_k<64, 9, 2, false, false, 3><<<1876, B, 0, stream>>>(
        upA, inv13, Wt1, rawB, inv31, Wt2, rawC, 938, NC, NC, 9, 9, NC, NC);
    stats2_k<<<240, B, 0, stream>>>(rawB, rawC, sums1, sums2, 120);
    finalize_k<<<1, 64, 0, stream>>>(sums1, g1, b1, scsh1);
    finalize_k<<<1, 64, 0, stream>>>(sums2, g2, b2, scsh2);

    apply12_k<<<((NC + 1) * 64 + 255) / 256, B, 0, stream>>>(rawB, rawC, scsh1, scsh2, upE);

    // upsample inverse conv -> d_out (float32), regime-split via dual problem:
    //   A: blocks 0-937, fine rows < NC (even parity): 1 tap (slot 0 = tap 13,
    //      identity gather).
    //   B: blocks 938-1875, fine rows >= NC (odd parity): 8 taps (slots 1-8),
    //      inv/out offset by NC.
    spconv_k<64, 8, 2, false, true, 3><<<1876, B, 0, stream>>>(
        upE, inv_up, WtU, outp,
        inv_up + (size_t)NF + NC, WtU + 64 * 64, (void*)(outp + (size_t)NC * 64),
        938, NF, NF, 1, 8, NC, NC);
}